// Round 7
// baseline (1361.828 us; speedup 1.0000x reference)
//
#include <hip/hip_runtime.h>
#include <math.h>

#define NN 50000
#define NE 600000
#define NG 512

typedef unsigned int u32;
typedef unsigned short u16;

__device__ __forceinline__ float bf2f(u16 u) {
  return __uint_as_float(((u32)u) << 16);
}
__device__ __forceinline__ u16 f2bf(float f) {
  u32 u = __float_as_uint(f);
  u32 lsb = (u >> 16) & 1u;
  u += 0x7fffu + lsb;          // RNE
  return (u16)(u >> 16);
}

// ================= CSR build (once per launch) ========
__global__ __launch_bounds__(256)
void deg_count_k(const int* __restrict__ ei, int* __restrict__ deg) {
  int e = blockIdx.x * 256 + threadIdx.x;
  if (e >= NE) return;
  atomicAdd(&deg[ei[NE + e]], 1);
}

__global__ __launch_bounds__(1024)
void scan_k(const int* __restrict__ deg, int* __restrict__ row_ptr, int* __restrict__ cursor) {
  __shared__ int sums[1024];
  const int CH = 49;                 // 1024*49 = 50176 >= 50000
  int t = threadIdx.x;
  int base = t * CH;
  int s = 0;
  for (int i = 0; i < CH; i++) { int idx = base + i; if (idx < NN) s += deg[idx]; }
  sums[t] = s;
  __syncthreads();
  for (int off = 1; off < 1024; off <<= 1) {
    int v = (t >= off) ? sums[t - off] : 0;
    __syncthreads();
    sums[t] += v;
    __syncthreads();
  }
  int prefix = (t == 0) ? 0 : sums[t - 1];
  for (int i = 0; i < CH; i++) {
    int idx = base + i;
    if (idx < NN) { row_ptr[idx] = prefix; cursor[idx] = prefix; prefix += deg[idx]; }
  }
  if (t == 1023) row_ptr[NN] = sums[1023];
}

__global__ __launch_bounds__(256)
void fill_k(const int* __restrict__ ei, int* __restrict__ cursor, int* __restrict__ perm) {
  int e = blockIdx.x * 256 + threadIdx.x;
  if (e >= NE) return;
  int pos = atomicAdd(&cursor[ei[NE + e]], 1);
  perm[pos] = ei[e];
}

// ================= cast x (f32) -> xb (bf16) =================
__global__ __launch_bounds__(256)
void cast_k(const float* __restrict__ x, u32* __restrict__ xb) {
  int tid = blockIdx.x * 256 + threadIdx.x;       // 12500*256 = 3,200,000 exactly
  float2 v = ((const float2*)x)[tid];
  xb[tid] = (u32)f2bf(v.x) | ((u32)f2bf(v.y) << 16);
}

// ===== gather-mean from bf16 features: agg[n] = mean_{e in(n)} xb[perm[e]] (f32 out) =====
// one wave per node; lane owns channels (2*lane, 2*lane+1) = one u32.
// ALWAYS full batches of 8 independent loads (index clamped, accumulate predicated) -> no
// serial remainder chain.
__global__ __launch_bounds__(256)
void gather_bf_k(const u16* __restrict__ xb, const int* __restrict__ row_ptr,
                 const int* __restrict__ perm, float* __restrict__ agg) {
  int wave = threadIdx.x >> 6;
  int lane = threadIdx.x & 63;
  int n = blockIdx.x * 4 + wave;          // 12500 * 4 = 50000
  int beg = row_ptr[n], end = row_ptr[n + 1];
  int cnt = end - beg;
  int co = lane * 2;
  float ax[8], ay[8];
#pragma unroll
  for (int j = 0; j < 8; j++) { ax[j] = 0.f; ay[j] = 0.f; }
  for (int base = 0; base < cnt; base += 8) {
    int rem = cnt - base;                 // wave-uniform, >0
    int last = rem - 1;
    int idx[8];
#pragma unroll
    for (int j = 0; j < 8; j++) idx[j] = perm[beg + base + min(j, last)];
    u32 u[8];
#pragma unroll
    for (int j = 0; j < 8; j++) u[j] = *(const u32*)(xb + (size_t)idx[j] * 128 + co);
#pragma unroll
    for (int j = 0; j < 8; j++) {
      bool live = j < rem;
      ax[j] += live ? __uint_as_float(u[j] << 16) : 0.f;
      ay[j] += live ? __uint_as_float(u[j] & 0xffff0000u) : 0.f;
    }
  }
  float sx = (ax[0]+ax[1])+(ax[2]+ax[3])+((ax[4]+ax[5])+(ax[6]+ax[7]));
  float sy = (ay[0]+ay[1])+(ay[2]+ay[3])+((ay[4]+ay[5])+(ay[6]+ay[7]));
  float inv = 1.0f / fmaxf((float)cnt, 1.0f);
  float2 o = { sx * inv, sy * inv };
  *(float2*)(agg + (size_t)n * 128 + co) = o;
}

// ===== SAGE layer Cout=128: out = agg@Wl + bl + x@Wr =====
// block 256 = 4 waves; wave owns 4 rows; lane owns cols (2*lane, 2*lane+1).
// Block's 16 rows (agg + x) staged in LDS once (coalesced); W in 4 x 32KB chunks.
// Inner loop: vin = same-address LDS broadcast, w = ds_read_b64. LDS total 48KB -> 3 blk/CU.
template<bool WRITE_PRE, bool WRITE_RELU_F32>
__global__ __launch_bounds__(256)
void sage128_k(const float* __restrict__ x, const float* __restrict__ agg,
               const float* __restrict__ Wl, const float* __restrict__ bl,
               const float* __restrict__ Wr,
               float* __restrict__ out_relu, float* __restrict__ out_pre,
               u16* __restrict__ xb_out) {
  __shared__ __align__(16) float sW[64 * 128];     // 32 KB chunk
  __shared__ __align__(16) float sR[2][16][128];   // 16 KB: [0]=agg rows, [1]=x rows
  int wave = threadIdx.x >> 6;
  int lane = threadIdx.x & 63;
  int rb = blockIdx.x * 16;                        // 3125 * 16 = 50000
  int r0 = rb + wave * 4;
  int co = lane * 2;

  // stage the block's rows (visibility covered by first W-stage barrier)
  {
    const float4* ga = (const float4*)(agg + (size_t)rb * 128);
    const float4* gx = (const float4*)(x   + (size_t)rb * 128);
    float4* s0 = (float4*)&sR[0][0][0];
    float4* s1 = (float4*)&sR[1][0][0];
    for (int t = threadIdx.x; t < 512; t += 256) { s0[t] = ga[t]; s1[t] = gx[t]; }
  }

  float acc0[4] = {0.f, 0.f, 0.f, 0.f};
  float acc1[4] = {0.f, 0.f, 0.f, 0.f};

  for (int half = 0; half < 4; half++) {
    const float* Wg = (half < 2) ? Wl : Wr;
    int sel = (half < 2) ? 0 : 1;
    int kbase = (half & 1) * 64;
    __syncthreads();
    {
      const float4* g = (const float4*)(Wg + kbase * 128);
      float4* s = (float4*)sW;
      for (int t = threadIdx.x; t < 2048; t += 256) s[t] = g[t];
    }
    __syncthreads();
    for (int kb = 0; kb < 8; kb++) {
      int k0 = kb * 8;
      float w0[8], w1[8];
#pragma unroll
      for (int j = 0; j < 8; j++) {
        float2 wp = *(const float2*)(&sW[(k0 + j) * 128 + co]);
        w0[j] = wp.x; w1[j] = wp.y;
      }
#pragma unroll
      for (int i = 0; i < 4; i++) {
        float4 a0 = *(const float4*)(&sR[sel][wave * 4 + i][kbase + k0]);
        float4 a1 = *(const float4*)(&sR[sel][wave * 4 + i][kbase + k0 + 4]);
        float vin[8] = {a0.x, a0.y, a0.z, a0.w, a1.x, a1.y, a1.z, a1.w};
#pragma unroll
        for (int j = 0; j < 8; j++) {
          acc0[i] = fmaf(vin[j], w0[j], acc0[i]);
          acc1[i] = fmaf(vin[j], w1[j], acc1[i]);
        }
      }
    }
  }
  float2 bp = *(const float2*)(bl + co);
#pragma unroll
  for (int i = 0; i < 4; i++) {
    int r = r0 + i;
    float v0 = acc0[i] + bp.x;
    float v1 = acc1[i] + bp.y;
    if (WRITE_PRE) {
      float2 p = {v0, v1};
      *(float2*)(out_pre + (size_t)r * 128 + co) = p;
    }
    float r0f = fmaxf(v0, 0.0f), r1f = fmaxf(v1, 0.0f);
    if (WRITE_RELU_F32) {
      float2 q = {r0f, r1f};
      *(float2*)(out_relu + (size_t)r * 128 + co) = q;
    }
    *(u32*)(xb_out + (size_t)r * 128 + co) = (u32)f2bf(r0f) | ((u32)f2bf(r1f) << 16);
  }
}

// ===== final layer Cout=64 + log_softmax; rows staged in LDS (agg f32 + x bf16) =====
__global__ __launch_bounds__(256)
void sage64_k(const u16* __restrict__ xb, const float* __restrict__ agg,
              const float* __restrict__ Wl, const float* __restrict__ bl,
              const float* __restrict__ Wr,
              float* __restrict__ out) {
  __shared__ __align__(16) float sW[128 * 64];     // 32 KB (one full W per pass)
  __shared__ __align__(16) float sRa[16][128];     // 8 KB agg rows
  __shared__ __align__(16) u32   sRx[16][64];      // 4 KB bf16 rows (packed)
  int wave = threadIdx.x >> 6;
  int lane = threadIdx.x & 63;
  int rb = blockIdx.x * 16;
  int r0 = rb + wave * 4;

  {
    const float4* ga = (const float4*)(agg + (size_t)rb * 128);
    const uint4*  gx = (const uint4*)(xb + (size_t)rb * 128);
    float4* s0 = (float4*)&sRa[0][0];
    uint4*  s1 = (uint4*)&sRx[0][0];
    for (int t = threadIdx.x; t < 512; t += 256) s0[t] = ga[t];
    for (int t = threadIdx.x; t < 256; t += 256) s1[t] = gx[t];
  }

  float acc[4] = {0.f, 0.f, 0.f, 0.f};

  for (int pass = 0; pass < 2; pass++) {
    const float* Wg = pass ? Wr : Wl;
    __syncthreads();
    {
      const float4* g = (const float4*)Wg;
      float4* s = (float4*)sW;
      for (int t = threadIdx.x; t < 2048; t += 256) s[t] = g[t];
    }
    __syncthreads();
    for (int kb = 0; kb < 16; kb++) {
      int k0 = kb * 8;
      float w[8];
#pragma unroll
      for (int j = 0; j < 8; j++) w[j] = sW[(k0 + j) * 64 + lane];
#pragma unroll
      for (int i = 0; i < 4; i++) {
        float vin[8];
        if (pass == 0) {
          float4 a0 = *(const float4*)(&sRa[wave * 4 + i][k0]);
          float4 a1 = *(const float4*)(&sRa[wave * 4 + i][k0 + 4]);
          vin[0] = a0.x; vin[1] = a0.y; vin[2] = a0.z; vin[3] = a0.w;
          vin[4] = a1.x; vin[5] = a1.y; vin[6] = a1.z; vin[7] = a1.w;
        } else {
          uint4 xv = *(const uint4*)(&sRx[wave * 4 + i][k0 / 2]);
          vin[0] = __uint_as_float(xv.x << 16); vin[1] = __uint_as_float(xv.x & 0xffff0000u);
          vin[2] = __uint_as_float(xv.y << 16); vin[3] = __uint_as_float(xv.y & 0xffff0000u);
          vin[4] = __uint_as_float(xv.z << 16); vin[5] = __uint_as_float(xv.z & 0xffff0000u);
          vin[6] = __uint_as_float(xv.w << 16); vin[7] = __uint_as_float(xv.w & 0xffff0000u);
        }
#pragma unroll
        for (int j = 0; j < 8; j++) acc[i] = fmaf(vin[j], w[j], acc[i]);
      }
    }
  }
  float b = bl[lane];
#pragma unroll
  for (int i = 0; i < 4; i++) {
    float v = acc[i] + b;
    float m = v;
#pragma unroll
    for (int off = 32; off > 0; off >>= 1) m = fmaxf(m, __shfl_xor(m, off));
    float e = __expf(v - m);
    float s = e;
#pragma unroll
    for (int off = 32; off > 0; off >>= 1) s += __shfl_xor(s, off);
    float ls = v - m - __logf(s);
    out[(size_t)(r0 + i) * 64 + lane] = ls;
  }
}

// ======= graph pooling from bf16 x2 (cluster sorted -> segmented mean, no atomics) =======
__global__ __launch_bounds__(128)
void pool_seg_k(const u16* __restrict__ xb, const int* __restrict__ cluster,
                float* __restrict__ g) {
  int gid = blockIdx.x;          // 512
  int ch = threadIdx.x;          // 128
  int lo = 0, hi = NN;
  while (lo < hi) { int mid = (lo + hi) >> 1; if (cluster[mid] < gid) lo = mid + 1; else hi = mid; }
  int beg = lo;
  hi = NN;
  while (lo < hi) { int mid = (lo + hi) >> 1; if (cluster[mid] < gid + 1) lo = mid + 1; else hi = mid; }
  int end = lo;
  float s0 = 0.f, s1 = 0.f, s2 = 0.f, s3 = 0.f;
  int n = beg;
  for (; n + 4 <= end; n += 4) {
    s0 += bf2f(xb[(size_t)(n + 0) * 128 + ch]);
    s1 += bf2f(xb[(size_t)(n + 1) * 128 + ch]);
    s2 += bf2f(xb[(size_t)(n + 2) * 128 + ch]);
    s3 += bf2f(xb[(size_t)(n + 3) * 128 + ch]);
  }
  for (; n < end; n++) s0 += bf2f(xb[(size_t)n * 128 + ch]);
  float s = (s0 + s1) + (s2 + s3);
  g[gid * 128 + ch] = s / fmaxf((float)(end - beg), 1.0f);
}

extern "C" void kernel_launch(void* const* d_in, const int* in_sizes, int n_in,
                              void* d_out, int out_size, void* d_ws, size_t ws_size,
                              hipStream_t stream) {
  const float* x   = (const float*)d_in[0];
  const int*   ei  = (const int*)d_in[1];
  const int*   cl  = (const int*)d_in[2];
  const float* Wl0 = (const float*)d_in[3];
  const float* bl0 = (const float*)d_in[4];
  const float* Wr0 = (const float*)d_in[5];
  const float* Wl1 = (const float*)d_in[6];
  const float* bl1 = (const float*)d_in[7];
  const float* Wr1 = (const float*)d_in[8];
  const float* Wl2 = (const float*)d_in[9];
  const float* bl2 = (const float*)d_in[10];
  const float* Wr2 = (const float*)d_in[11];
  float* out = (float*)d_out;

  char* ws = (char*)d_ws;
  float* x1      = (float*)(ws);                  // 25,600,000 B (f32 relu of layer0)
  float* agg     = (float*)(ws + 25600000);       // 25,600,000 B
  u16*   xb      = (u16*)  (ws + 51200000);       // 12,800,000 B (bf16 mirror, reused per layer)
  int*   deg     = (int*)  (ws + 64000000);       //    200,000 B
  int*   row_ptr = (int*)  (ws + 64200192);       //    200,004 B (+pad)
  int*   cursor  = (int*)  (ws + 64400896);       //    200,000 B
  int*   perm    = (int*)  (ws + 64600896);       //  2,400,000 B

  float* out_lsm = out;            // [50000,64]
  float* out_pre = out + 3200000;  // [50000,128]
  float* out_g   = out + 9600000;  // [512,128]

  // ---- CSR build (once) ----
  hipMemsetAsync(deg, 0, 200000, stream);
  deg_count_k<<<2344, 256, 0, stream>>>(ei, deg);
  scan_k<<<1, 1024, 0, stream>>>(deg, row_ptr, cursor);
  fill_k<<<2344, 256, 0, stream>>>(ei, cursor, perm);

  // ---- layer 0 ----
  cast_k<<<12500, 256, 0, stream>>>(x, (u32*)xb);
  gather_bf_k<<<12500, 256, 0, stream>>>(xb, row_ptr, perm, agg);
  sage128_k<false, true><<<3125, 256, 0, stream>>>(x, agg, Wl0, bl0, Wr0, x1, nullptr, xb);

  // ---- layer 1 (pre-relu f32 straight to d_out; relu only as bf16 mirror) ----
  gather_bf_k<<<12500, 256, 0, stream>>>(xb, row_ptr, perm, agg);
  sage128_k<true, false><<<3125, 256, 0, stream>>>(x1, agg, Wl1, bl1, Wr1, nullptr, out_pre, xb);

  // ---- graph pooling of x2 (bf16) ----
  pool_seg_k<<<NG, 128, 0, stream>>>(xb, cl, out_g);

  // ---- final layer + log_softmax ----
  gather_bf_k<<<12500, 256, 0, stream>>>(xb, row_ptr, perm, agg);
  sage64_k<<<3125, 256, 0, stream>>>(xb, agg, Wl2, bl2, Wr2, out_lsm);
}